// Round 14
// baseline (432.249 us; speedup 1.0000x reference)
//
#include <hip/hip_runtime.h>
#include <math.h>

#define NB 8
#define NS 32768
#define SEQ 128
#define DIM 128
#define KER 512
#define PI_D 3.14159265358979323846

#define ALOAD(p)     __hip_atomic_load((p), __ATOMIC_RELAXED, __HIP_MEMORY_SCOPE_AGENT)
#define ASTORE(p, v) __hip_atomic_store((p), (v), __ATOMIC_RELAXED, __HIP_MEMORY_SCOPE_AGENT)

typedef __attribute__((ext_vector_type(8))) short bfrag;
typedef __attribute__((ext_vector_type(16))) float f32x16;

__device__ __forceinline__ unsigned short bf_rne(float v) {
    unsigned int u = __float_as_uint(v);
    unsigned int r = u + 0x7FFFu + ((u >> 16) & 1u);
    return (unsigned short)(r >> 16);
}

// ---------------- fused prep: bfsplit(x) | fpack(filters) | pos+ham ----------------
__global__ void prep_k(const float* __restrict__ x, const float* __restrict__ F,
                       unsigned short* __restrict__ xhi, unsigned short* __restrict__ xlo,
                       unsigned short* __restrict__ Fph, unsigned short* __restrict__ Fpl,
                       float* __restrict__ posT, float* __restrict__ ham) {
    int bid = blockIdx.x, t = threadIdx.x;
    if (bid < 1024) {                      // bfsplit of x: 262144 elems
        int i = bid * 256 + t;
        float v = x[i];
        unsigned short h = bf_rne(v);
        float hf = __uint_as_float(((unsigned int)h) << 16);
        xhi[i] = h;
        xlo[i] = bf_rne(v - hf);
    } else if (bid < 1280) {               // fpack: 65536 elems
        int idx = (bid - 1024) * 256 + t;
        int e = idx & 7, lane = (idx >> 3) & 63, step = (idx >> 9) & 31, mt = idx >> 14;
        int row = mt * 32 + (lane & 31);
        int k = step * 16 + (lane >> 5) * 8 + e;
        float v = F[row * 512 + k];
        unsigned short h = bf_rne(v);
        float hf = __uint_as_float(((unsigned int)h) << 16);
        Fph[idx] = h;
        Fpl[idx] = bf_rne(v - hf);
    } else {                               // pos + ham
        if (t < 128) {
            double p = (double)((float)(-1.0 + 2.0 * (double)t / 127.0));
            posT[t * 33 + 0] = (float)p;
            for (int i = 0; i < 16; ++i) {
                double a = ldexp(p, i) * PI_D;
                posT[t * 33 + 1 + 2 * i] = (float)sin(a);
                posT[t * 33 + 2 + 2 * i] = (float)cos(a);
            }
        }
#pragma unroll
        for (int i = 0; i < 2; ++i) {
            int w = t + i * 256;
            ham[w] = (float)(0.54 - 0.46 * cos(2.0 * PI_D * (double)w / 511.0));
        }
    }
}

// ---------------- conv + abs + pool: 2 chunks (512 samples) per block ----------------
__global__ void __launch_bounds__(512) conv_mfma_k(
        const unsigned short* __restrict__ xhi, const unsigned short* __restrict__ xlo,
        const unsigned short* __restrict__ Fph, const unsigned short* __restrict__ Fpl,
        float* __restrict__ P) {
    int cp = blockIdx.x, b = blockIdx.y;   // cp in [0,64): chunks 2cp, 2cp+1
    int t = threadIdx.x;
    __shared__ __align__(16) unsigned short xsh[8][1032];
    __shared__ __align__(16) unsigned short xsl[8][1032];
    __shared__ float Pp[2][128];
    int base = cp * 512 - 256;
    for (int j = t; j < 1024; j += 512) {
        int gi = base + j;
        unsigned short h = 0, l = 0;
        if (gi >= 0 && gi < NS) { h = xhi[b * NS + gi]; l = xlo[b * NS + gi]; }
#pragma unroll
        for (int r = 0; r < 8; ++r) {
            int slot = j - r;
            if (slot >= 0) { xsh[r][slot] = h; xsl[r][slot] = l; }
        }
    }
    if (t < 256) Pp[t >> 7][t & 127] = 0.f;
    __syncthreads();

    int wid = t >> 6, lane = t & 63;
    int col = lane & 31, g = lane >> 5;
    int mbase = (wid & 1) * 64;
    int nbase = (wid >> 1) * 64;
    int rsel = col & 7;
    int p0 = nbase + col + 8 * g - rsel;
    int mt0 = (wid & 1) * 2;
    const unsigned short* aph = Fph + (size_t)mt0 * 16384 + lane * 8;
    const unsigned short* apl = Fpl + (size_t)mt0 * 16384 + lane * 8;

#pragma unroll
    for (int chunk = 0; chunk < 2; ++chunk) {
        const bfrag* bh0 = (const bfrag*)&xsh[rsel][p0 + chunk * 256];
        const bfrag* bl0 = (const bfrag*)&xsl[rsel][p0 + chunk * 256];
        const bfrag* bh1 = (const bfrag*)&xsh[rsel][p0 + chunk * 256 + 32];
        const bfrag* bl1 = (const bfrag*)&xsl[rsel][p0 + chunk * 256 + 32];

        f32x16 c00, c01, c10, c11;
#pragma unroll
        for (int r = 0; r < 16; ++r) { c00[r] = 0.f; c01[r] = 0.f; c10[r] = 0.f; c11[r] = 0.f; }

        bfrag ch0 = *(const bfrag*)(aph);
        bfrag ch1 = *(const bfrag*)(aph + 16384);
        bfrag cl0 = *(const bfrag*)(apl);
        bfrag cl1 = *(const bfrag*)(apl + 16384);
        bfrag dh0 = bh0[0], dl0 = bl0[0], dh1 = bh1[0], dl1 = bl1[0];
#pragma unroll 2
        for (int step = 0; step < 32; ++step) {
            int sn = (step < 31) ? step + 1 : 31;
            bfrag nh0 = *(const bfrag*)(aph + sn * 512);
            bfrag nh1 = *(const bfrag*)(aph + 16384 + sn * 512);
            bfrag nl0 = *(const bfrag*)(apl + sn * 512);
            bfrag nl1 = *(const bfrag*)(apl + 16384 + sn * 512);
            bfrag mh0 = bh0[2 * sn], ml0 = bl0[2 * sn];
            bfrag mh1 = bh1[2 * sn], ml1 = bl1[2 * sn];
            c00 = __builtin_amdgcn_mfma_f32_32x32x16_bf16(ch0, dh0, c00, 0, 0, 0);
            c00 = __builtin_amdgcn_mfma_f32_32x32x16_bf16(ch0, dl0, c00, 0, 0, 0);
            c00 = __builtin_amdgcn_mfma_f32_32x32x16_bf16(cl0, dh0, c00, 0, 0, 0);
            c01 = __builtin_amdgcn_mfma_f32_32x32x16_bf16(ch0, dh1, c01, 0, 0, 0);
            c01 = __builtin_amdgcn_mfma_f32_32x32x16_bf16(ch0, dl1, c01, 0, 0, 0);
            c01 = __builtin_amdgcn_mfma_f32_32x32x16_bf16(cl0, dh1, c01, 0, 0, 0);
            c10 = __builtin_amdgcn_mfma_f32_32x32x16_bf16(ch1, dh0, c10, 0, 0, 0);
            c10 = __builtin_amdgcn_mfma_f32_32x32x16_bf16(ch1, dl0, c10, 0, 0, 0);
            c10 = __builtin_amdgcn_mfma_f32_32x32x16_bf16(cl1, dh0, c10, 0, 0, 0);
            c11 = __builtin_amdgcn_mfma_f32_32x32x16_bf16(ch1, dh1, c11, 0, 0, 0);
            c11 = __builtin_amdgcn_mfma_f32_32x32x16_bf16(ch1, dl1, c11, 0, 0, 0);
            c11 = __builtin_amdgcn_mfma_f32_32x32x16_bf16(cl1, dh1, c11, 0, 0, 0);
            ch0 = nh0; ch1 = nh1; cl0 = nl0; cl1 = nl1;
            dh0 = mh0; dl0 = ml0; dh1 = mh1; dl1 = ml1;
        }

#pragma unroll
        for (int r = 0; r < 16; ++r) {
            float s0 = fabsf(c00[r]) + fabsf(c01[r]);
            float s1 = fabsf(c10[r]) + fabsf(c11[r]);
#pragma unroll
            for (int m = 1; m <= 16; m <<= 1) { s0 += __shfl_xor(s0, m); s1 += __shfl_xor(s1, m); }
            if ((lane & 31) == 0) {
                int rowoff = (r & 3) + 8 * (r >> 2) + 4 * g;
                atomicAdd(&Pp[chunk][mbase + rowoff], s0);
                atomicAdd(&Pp[chunk][mbase + 32 + rowoff], s1);
            }
        }
    }
    __syncthreads();
    if (t < 256) P[((size_t)b * 128 + (t & 127)) * 128 + cp * 2 + (t >> 7)] = Pp[t >> 7][t & 127];
}

// ---------------- weight packing: W[N][K] -> [ct][kt][64] float4 ----------------
struct PackPtrs { const float* p[51]; };

__global__ void pack_k(PackPtrs pp, float4* __restrict__ dst) {
    int m = blockIdx.y;
    const float* src = pp.p[m];
    int N, K, KT; size_t off;
    if (m < 12)      { N = 384; K = 128; KT = 32; off = (size_t)m * 12288; }
    else if (m < 24) { N = 128; K = 128; KT = 32; off = 147456 + (size_t)(m - 12) * 4096; }
    else if (m < 36) { N = 128; K = 128; KT = 32; off = 196608 + (size_t)(m - 24) * 4096; }
    else if (m < 48) { N = 128; K = 128; KT = 32; off = 245760 + (size_t)(m - 36) * 4096; }
    else if (m == 48){ N = 128; K = 161; KT = 41; off = 294912; }
    else if (m == 49){ N = 128; K = 161; KT = 41; off = 300160; }
    else             { N = 512; K = 128; KT = 32; off = 305408; }
    int idx = blockIdx.x * 256 + threadIdx.x;
    int total = (N >> 6) * KT * 64;
    if (idx >= total) return;
    int ln = idx & 63;
    int kt = (idx >> 6) % KT;
    int ct = idx / (KT * 64);
    int cc = ct * 64 + ln;
    int k0 = kt * 4;
    float4 v;
    v.x = (k0 + 0 < K) ? src[(size_t)cc * K + k0 + 0] : 0.f;
    v.y = (k0 + 1 < K) ? src[(size_t)cc * K + k0 + 1] : 0.f;
    v.z = (k0 + 2 < K) ? src[(size_t)cc * K + k0 + 2] : 0.f;
    v.w = (k0 + 3 < K) ? src[(size_t)cc * K + k0 + 3] : 0.f;
    dst[off + idx] = v;
}

// ---------------- megakernel ----------------
struct MegaArgs {
    const float* b_qkv[12]; const float* b_o[12]; const float* b1[12]; const float* b2[12];
    const float* ln1g[12]; const float* ln1b[12]; const float* ln2g[12]; const float* ln2b[12];
    const float* embed_b; const float* embed2_b; const float* env_w; const float* env_b;
    const float* samp_b;
    const float* posT; const float* ham; const float* P;
    const float4* Wp;
    float* KV;    // 2 parities x 1024 rows x 256 (K|V)
    float* envbuf; float* Y; float* out;
    unsigned* ctr;
};

struct __align__(16) SM {
    float KV[128][129];   // attention staging
    union { float S[16][128]; float partial[16][128]; };
    float Aq[4][128];
    float Ax[4][128];
    float Ax2[4][128];
    float Ah[4][128];
    float cv[4][176];
    float red2[16];
    int   red2i[8];
    float tvals[128], tout[128], Linv[16];
};

__device__ __forceinline__ void gbarb(unsigned* ctr, unsigned& bi) {
    asm volatile("s_waitcnt vmcnt(0)" ::: "memory");
    __syncthreads();
    if (threadIdx.x == 0) {
        bi += 1;
        __hip_atomic_fetch_add(ctr, 1u, __ATOMIC_RELAXED, __HIP_MEMORY_SCOPE_AGENT);
        unsigned target = bi * 32u;
        while (__hip_atomic_load(ctr, __ATOMIC_RELAXED, __HIP_MEMORY_SCOPE_AGENT) < target) {
            __builtin_amdgcn_s_sleep(1);
        }
    }
    __syncthreads();
}

// full-K per-thread dot (KT=32 matrices), pressure-capped: 8 loads in flight
__device__ __forceinline__ float dot32(const float* Ar, const float4* Wp, int c) {
    float acc = 0.f;
#pragma unroll 1
    for (int kb = 0; kb < 4; ++kb) {
#pragma unroll
        for (int j = 0; j < 8; ++j) {
            int kt = kb * 8 + j;
            float4 a = *(const float4*)(Ar + kt * 4);
            float4 w = Wp[((size_t)((c >> 6) * 32 + kt)) * 64 + (c & 63)];
            acc += a.x * w.x + a.y * w.y + a.z * w.z + a.w * w.w;
        }
    }
    return acc;
}

// generic K-split path (embed only, KT=41)
template <int NCB>
__device__ __forceinline__ void gemm_acc(const float* A, int astride, const float4* Wp,
                                         int KT, int t, float (*acc)[4]) {
    int cidx = t & 127, kq = t >> 7;
    int KTq = (KT + 3) >> 2;
    int kt0 = kq * KTq;
    int kt1 = kt0 + KTq; if (kt1 > KT) kt1 = KT;
#pragma unroll
    for (int i = 0; i < NCB; ++i) { acc[i][0] = 0.f; acc[i][1] = 0.f; acc[i][2] = 0.f; acc[i][3] = 0.f; }
    for (int kt = kt0; kt < kt1; ++kt) {
        float4 a0 = *(const float4*)(A + 0 * astride + kt * 4);
        float4 a1 = *(const float4*)(A + 1 * astride + kt * 4);
        float4 a2 = *(const float4*)(A + 2 * astride + kt * 4);
        float4 a3 = *(const float4*)(A + 3 * astride + kt * 4);
#pragma unroll
        for (int i = 0; i < NCB; ++i) {
            int cb = cidx + i * 128;
            float4 w = Wp[((size_t)((cb >> 6) * KT + kt)) * 64 + (cb & 63)];
            acc[i][0] += a0.x * w.x + a0.y * w.y + a0.z * w.z + a0.w * w.w;
            acc[i][1] += a1.x * w.x + a1.y * w.y + a1.z * w.z + a1.w * w.w;
            acc[i][2] += a2.x * w.x + a2.y * w.y + a2.z * w.z + a2.w * w.w;
            acc[i][3] += a3.x * w.x + a3.y * w.y + a3.z * w.z + a3.w * w.w;
        }
    }
}

__device__ __forceinline__ float gemm_reduce(const float* a4, int t, SM& sm) {
    int cidx = t & 127, kq = t >> 7;
    __syncthreads();
#pragma unroll
    for (int r = 0; r < 4; ++r) sm.partial[r * 4 + kq][cidx] = a4[r];
    __syncthreads();
    int rsel = t >> 7;
    return sm.partial[rsel * 4 + 0][cidx] + sm.partial[rsel * 4 + 1][cidx]
         + sm.partial[rsel * 4 + 2][cidx] + sm.partial[rsel * 4 + 3][cidx];
}

// lnorm with NO trailing barrier (red2's next writer is >=1 barrier past all reads)
__device__ __forceinline__ float lnorm(float v, int t, const float* g, const float* be, SM& sm) {
    float s = v, s2 = v * v;
#pragma unroll
    for (int mm = 1; mm <= 32; mm <<= 1) { s += __shfl_xor(s, mm); s2 += __shfl_xor(s2, mm); }
    int w = t >> 6;
    if ((t & 63) == 0) { sm.red2[w * 2] = s; sm.red2[w * 2 + 1] = s2; }
    __syncthreads();
    int r = t >> 7;
    float S = sm.red2[(2 * r) * 2] + sm.red2[(2 * r + 1) * 2];
    float S2 = sm.red2[(2 * r) * 2 + 1] + sm.red2[(2 * r + 1) * 2 + 1];
    float mu = S * (1.f / 128.f);
    float var = S2 * (1.f / 128.f) - mu * mu;
    return (v - mu) * rsqrtf(var + 1e-5f) * g[t & 127] + be[t & 127];
}

// qkv: 3 sequential barrier-free full-K dots
__device__ __forceinline__ void qkv_tail(const MegaArgs& a, SM& sm, int l, int t, int rowbase) {
    const float4* qkvp = a.Wp + (size_t)l * 12288;
    int c = t & 127, r = t >> 7;
    const float* Ar = &sm.Ax[r][0];
    const float* bq = a.b_qkv[l];
    float* KVp = a.KV + (size_t)(l & 1) * 262144;
    float vq = dot32(Ar, qkvp, c) + bq[c];
    sm.Aq[r][c] = vq;
    float vk = dot32(Ar, qkvp + 4096, c) + bq[128 + c];
    ASTORE(&KVp[(size_t)(rowbase + r) * 256 + c], vk);
    float vv = dot32(Ar, qkvp + 8192, c) + bq[256 + c];
    ASTORE(&KVp[(size_t)(rowbase + r) * 256 + 128 + c], vv);
}

__global__ void __launch_bounds__(512, 1) mega_k(MegaArgs a) {
    __shared__ SM sm;
    const int t = threadIdx.x;
    const int bid = blockIdx.x;
    const int rowbase = bid * 4;
    const int b = rowbase >> 7;
    const int tfr = rowbase & 127;
    const int c = t & 127;
    const int rs = t >> 7;
    unsigned bctr = 0;
    unsigned* myctr = a.ctr + b * 16;

    const float4* embedp  = a.Wp + 294912;
    const float4* embed2p = a.Wp + 300160;
    const float4* sampp   = a.Wp + 305408;

    // ---- prologue: embed + qkv layer0 ----
    {
        int tf = tfr + rs;
        for (int j = c; j < 176; j += 128) {
            float val = 0.f;
            if (j < 33) val = a.posT[tf * 33 + j];
            else if (j < 161) {
                int o = j - 33;
                float p1 = a.P[((size_t)(b * 128 + o)) * 128 + tf];
                float p0 = (tf > 0) ? a.P[((size_t)(b * 128 + o)) * 128 + tf - 1] : 0.f;
                val = (p0 + p1) * (1.f / 512.f);
            }
            sm.cv[rs][j] = val;
        }
        __syncthreads();
        float acc1[1][4];
        gemm_acc<1>(&sm.cv[0][0], 176, embedp, 41, t, acc1);
        float v = gemm_reduce(acc1[0], t, sm) + a.embed_b[c];
        sm.Ax[rs][c] = v;
        __syncthreads();
        qkv_tail(a, sm, 0, t, rowbase);
        gbarb(myctr, bctr);
    }

    for (int l = 0; l < 12; ++l) {
        if (l == 6) {
            // ---- mid: env softmax + top16 + embed2 + qkv dec0 ----
            float v = (t < 128) ? ALOAD(&a.envbuf[b * 128 + t]) : -1e30f;
            float m_ = v;
#pragma unroll
            for (int mm = 1; mm <= 32; mm <<= 1) m_ = fmaxf(m_, __shfl_xor(m_, mm));
            if ((t & 63) == 0) sm.red2[(t >> 6) * 2] = m_;
            __syncthreads();
            float mx = fmaxf(sm.red2[0], sm.red2[2]);
            float e = (t < 128) ? expf(v - mx) : 0.f;
            float ssum = e;
#pragma unroll
            for (int mm = 1; mm <= 32; mm <<= 1) ssum += __shfl_xor(ssum, mm);
            __syncthreads();
            if ((t & 63) == 0) sm.red2[(t >> 6) * 2 + 1] = ssum;
            __syncthreads();
            float lsum = sm.red2[1] + sm.red2[3];
            if (t < 128) { sm.tvals[t] = e / lsum; sm.tout[t] = 0.f; }
            __syncthreads();
            for (int it = 0; it < 16; ++it) {
                float cv_ = (t < 128) ? sm.tvals[t] : -2.f;
                int ci = t & 127;
#pragma unroll
                for (int mm = 1; mm <= 32; mm <<= 1) {
                    float ov = __shfl_xor(cv_, mm);
                    int oi = __shfl_xor(ci, mm);
                    if (ov > cv_ || (ov == cv_ && oi < ci)) { cv_ = ov; ci = oi; }
                }
                if ((t & 63) == 0) { sm.red2[(t >> 6) * 2] = cv_; sm.red2i[t >> 6] = ci; }
                __syncthreads();
                if (t == 0) {
                    float v0 = sm.red2[0], v1 = sm.red2[2];
                    int i0 = sm.red2i[0], i1 = sm.red2i[1];
                    float bv; int bi2;
                    if (v1 > v0 || (v1 == v0 && i1 < i0)) { bv = v1; bi2 = i1; }
                    else { bv = v0; bi2 = i0; }
                    sm.tout[bi2] = bv;
                    sm.tvals[bi2] = -3.f;
                }
                __syncthreads();
            }
            float sclr = sm.tout[tfr + rs];
            for (int j = c; j < 176; j += 128) {
                float val = 0.f;
                if (j < 33) val = a.posT[(tfr + rs) * 33 + j];
                else if (j < 161) val = sm.Ax[rs][j - 33] * sclr;
                sm.cv[rs][j] = val;
            }
            __syncthreads();
            float acc1[1][4];
            gemm_acc<1>(&sm.cv[0][0], 176, embed2p, 41, t, acc1);
            float vv = gemm_reduce(acc1[0], t, sm) + a.embed2_b[c];
            sm.Ax[rs][c] = vv;
            __syncthreads();
            qkv_tail(a, sm, 6, t, rowbase);
            gbarb(myctr, bctr);
        }

        const float4* op  = a.Wp + 147456 + (size_t)l * 4096;
        const float4* w1p = a.Wp + 196608 + (size_t)l * 4096;
        const float4* w2p = a.Wp + 245760 + (size_t)l * 4096;
        const float* KVg = a.KV + (size_t)(l & 1) * 262144 + (size_t)b * 32768;

        // ---- A: attention (coalesced device-coherent loads -> LDS transpose) ----
        {
            float kst[32], vst[32];
#pragma unroll
            for (int j = 0; j < 32; ++j) {
                int f = j * 512 + t;
                kst[j] = ALOAD(&KVg[(size_t)(f >> 7) * 256 + (f & 127)]);
            }
#pragma unroll
            for (int j = 0; j < 32; ++j) {
                int f = j * 512 + t;
                vst[j] = ALOAD(&KVg[(size_t)(f >> 7) * 256 + 128 + (f & 127)]);
            }
            int cd = t & 127, r0 = t >> 7;
#pragma unroll
            for (int j = 0; j < 32; ++j) sm.KV[cd][j * 4 + r0] = kst[j];
            __syncthreads();
            {   // QK^T
                int h = t >> 7, k = c;
                float s0 = 0.f, s1 = 0.f, s2 = 0.f, s3 = 0.f;
#pragma unroll
                for (int d = 0; d < 32; ++d) {
                    float kvv = sm.KV[h * 32 + d][k];
                    s0 += sm.Aq[0][h * 32 + d] * kvv;
                    s1 += sm.Aq[1][h * 32 + d] * kvv;
                    s2 += sm.Aq[2][h * 32 + d] * kvv;
                    s3 += sm.Aq[3][h * 32 + d] * kvv;
                }
                const float scl = 0.17677669529663687f;
                sm.S[h * 4 + 0][k] = s0 * scl;
                sm.S[h * 4 + 1][k] = s1 * scl;
                sm.S[h * 4 + 2][k] = s2 * scl;
                sm.S[h * 4 + 3][k] = s3 * scl;
            }
            __syncthreads();
#pragma unroll
            for (int j = 0; j < 32; ++j) sm.KV[cd][j * 4 + r0] = vst[j];
            {   // softmax
                int row = t >> 5, l32 = t & 31;
                float v0 = sm.S[row][l32], v1 = sm.S[row][l32 + 32];
                float v2 = sm.S[row][l32 + 64], v3 = sm.S[row][l32 + 96];
                float mx = fmaxf(fmaxf(v0, v1), fmaxf(v2, v3));
#pragma unroll
                for (int mm = 1; mm <= 16; mm <<= 1) mx = fmaxf(mx, __shfl_xor(mx, mm));
                float e0 = __expf(v0 - mx), e1 = __expf(v1 - mx);
                float e2 = __expf(v2 - mx), e3 = __expf(v3 - mx);
                float ls = e0 + e1 + e2 + e3;
#pragma unroll
                for (int mm = 1; mm <= 16; mm <<= 1) ls += __shfl_xor(ls, mm);
                sm.S[row][l32] = e0; sm.S[row][l32 + 32] = e1;
                sm.S[row][l32 + 64] = e2; sm.S[row][l32 + 96] = e3;
                if (l32 == 0) sm.Linv[row] = 1.f / ls;
            }
            __syncthreads();
            {   // PV
                int h = t >> 7, r = (t >> 5) & 3, d = t & 31;
                const float* Pr = &sm.S[h * 4 + r][0];
                float o = 0.f;
#pragma unroll 8
                for (int k2 = 0; k2 < 128; ++k2) o += Pr[k2] * sm.KV[h * 32 + d][k2];
                sm.Ah[r][h * 32 + d] = o * sm.Linv[h * 4 + r];
            }
            __syncthreads();
        }
        // ---- o-proj + residual + ln1 (barrier-free dot) ----
        {
            float v = dot32(&sm.Ah[rs][0], op, c) + a.b_o[l][c] + sm.Ax[rs][c];
            v = lnorm(v, t, a.ln1g[l], a.ln1b[l], sm);   // 1 internal sync
            sm.Ax2[rs][c] = v;
            __syncthreads();
        }
        // ---- ffn1 (barrier-free dot; Ah write safe: >=2 syncs since last Ah read) ----
        {
            float v = fmaxf(dot32(&sm.Ax2[rs][0], w1p, c) + a.b1[l][c], 0.f);
            sm.Ah[rs][c] = v;
            __syncthreads();
        }
        // ---- ffn2 + residual + ln2 ----
        {
            float v2 = dot32(&sm.Ah[rs][0], w2p, c) + a.b2[l][c] + sm.Ax2[rs][c];
            v2 = lnorm(v2, t, a.ln2g[l], a.ln2b[l], sm);
            sm.Ax[rs][c] = v2;
            __syncthreads();
        }
        // ---- tail ----
        if (l == 5) {
            float pv = sm.Ax[rs][c] * a.env_w[c];
#pragma unroll
            for (int mm = 1; mm <= 32; mm <<= 1) pv += __shfl_xor(pv, mm);
            int w = t >> 6;
            if ((t & 63) == 0) sm.red2[w * 2] = pv;
            __syncthreads();
            if (t < 4) ASTORE(&a.envbuf[rowbase + t],
                              sm.red2[(2 * t) * 2] + sm.red2[(2 * t + 1) * 2] + a.env_b[0]);
            __syncthreads();
        } else if (l == 11) {
            // samp: 4 sequential barrier-free dots
            const float* Ar = &sm.Ax[rs][0];
#pragma unroll 1
            for (int i = 0; i < 4; ++i) {
                int cg = c + i * 128;
                float v = (dot32(Ar, sampp, cg) + a.samp_b[cg]) * a.ham[cg];
                ASTORE(&a.Y[((size_t)(rowbase + rs)) * 512 + cg], v);
            }
        } else {
            qkv_tail(a, sm, l + 1, t, rowbase);
        }
        gbarb(myctr, bctr);
    }

    // ---- overlap-add (batch-local) ----
    {
        int b32 = bid & 31;
#pragma unroll
        for (int i = 0; i < 2; ++i) {
            int il = b32 * 512 + t + i * 16384;
            int t0 = il >> 8, w0 = il & 255;
            float acc = ALOAD(&a.Y[((size_t)(b * 128 + t0)) * 512 + w0]);
            if (t0 > 0) acc += ALOAD(&a.Y[((size_t)(b * 128 + t0 - 1)) * 512 + w0 + 256]);
            a.out[(size_t)b * 32768 + il] = acc;
        }
    }
}

extern "C" void kernel_launch(void* const* d_in, const int* in_sizes, int n_in,
                              void* d_out, int out_size, void* d_ws, size_t ws_size,
                              hipStream_t stream) {
    const float* x        = (const float*)d_in[0];
    const float* filters  = (const float*)d_in[1];
    const float* embed_w  = (const float*)d_in[2];
    const float* embed_b  = (const float*)d_in[3];
    const float* embed2_w = (const float*)d_in[4];
    const float* embed2_b = (const float*)d_in[5];
    const float* env_w    = (const float*)d_in[6];
    const float* env_b    = (const float*)d_in[7];
    const float* samp_w   = (const float*)d_in[8];
    const float* samp_b   = (const float*)d_in[9];

    float* ws = (float*)d_ws;
    float* P     = ws;                      // 131072
    float* posT  = ws + 131072;             // 4352
    float* hamw  = ws + 135424;             // 512
    float* envb  = ws + 135936;             // 1024
    float* KV    = ws + 136960;             // 524288 (2 parities x 1024 x 256)
    float* Y     = ws + 661248;             // 524288
    float4* Wp   = (float4*)(ws + 1185536); // 321792 float4
    unsigned* ctr = (unsigned*)(ws + 2472704);
    // conv-prep aliases (dead regions at conv time)
    unsigned short* xhi = (unsigned short*)Y;
    unsigned short* xlo = (unsigned short*)(Y + 131072);
    unsigned short* Fph = (unsigned short*)KV;
    unsigned short* Fpl = (unsigned short*)(KV + 32768);

    prep_k<<<1281, 256, 0, stream>>>(x, filters, xhi, xlo, Fph, Fpl, posT, hamw);
    conv_mfma_k<<<dim3(64, 8), 512, 0, stream>>>(xhi, xlo, Fph, Fpl, P);

    PackPtrs pp;
    for (int l = 0; l < 12; ++l) {
        int base = (l < 6) ? 10 + l * 12 : 82 + (l - 6) * 12;
        pp.p[l]      = (const float*)d_in[base + 0];
        pp.p[12 + l] = (const float*)d_in[base + 2];
        pp.p[24 + l] = (const float*)d_in[base + 4];
        pp.p[36 + l] = (const float*)d_in[base + 6];
    }
    pp.p[48] = embed_w; pp.p[49] = embed2_w; pp.p[50] = samp_w;
    pack_k<<<dim3(64, 51), 256, 0, stream>>>(pp, Wp);

    hipMemsetAsync(ctr, 0, 1024, stream);

    MegaArgs ma;
    for (int l = 0; l < 12; ++l) {
        int base = (l < 6) ? 10 + l * 12 : 82 + (l - 6) * 12;
        ma.b_qkv[l] = (const float*)d_in[base + 1];
        ma.b_o[l]   = (const float*)d_in[base + 3];
        ma.b1[l]    = (const float*)d_in[base + 5];
        ma.b2[l]    = (const float*)d_in[base + 7];
        ma.ln1g[l]  = (const float*)d_in[base + 8];
        ma.ln1b[l]  = (const float*)d_in[base + 9];
        ma.ln2g[l]  = (const float*)d_in[base + 10];
        ma.ln2b[l]  = (const float*)d_in[base + 11];
    }
    ma.embed_b = embed_b; ma.embed2_b = embed2_b;
    ma.env_w = env_w; ma.env_b = env_b; ma.samp_b = samp_b;
    ma.posT = posT; ma.ham = hamw; ma.P = P;
    ma.Wp = (const float4*)Wp;
    ma.KV = KV; ma.envbuf = envb; ma.Y = Y; ma.out = (float*)d_out;
    ma.ctr = ctr;

    mega_k<<<256, 512, 0, stream>>>(ma);
}

// Round 15
// 341.906 us; speedup vs baseline: 1.2642x; 1.2642x over previous
//
#include <hip/hip_runtime.h>
#include <math.h>

#define NB 8
#define NS 32768
#define SEQ 128
#define DIM 128
#define KER 512
#define PI_D 3.14159265358979323846

#define ALOAD(p)     __hip_atomic_load((p), __ATOMIC_RELAXED, __HIP_MEMORY_SCOPE_AGENT)
#define ASTORE(p, v) __hip_atomic_store((p), (v), __ATOMIC_RELAXED, __HIP_MEMORY_SCOPE_AGENT)

typedef __attribute__((ext_vector_type(8))) short bfrag;
typedef __attribute__((ext_vector_type(16))) float f32x16;

__device__ __forceinline__ unsigned short bf_rne(float v) {
    unsigned int u = __float_as_uint(v);
    unsigned int r = u + 0x7FFFu + ((u >> 16) & 1u);
    return (unsigned short)(r >> 16);
}

// ---------------- fused prep: bfsplit(x) | fpack(filters) | pos+ham ----------------
__global__ void prep_k(const float* __restrict__ x, const float* __restrict__ F,
                       unsigned short* __restrict__ xhi, unsigned short* __restrict__ xlo,
                       unsigned short* __restrict__ Fph, unsigned short* __restrict__ Fpl,
                       float* __restrict__ posT, float* __restrict__ ham) {
    int bid = blockIdx.x, t = threadIdx.x;
    if (bid < 1024) {                      // bfsplit of x: 262144 elems
        int i = bid * 256 + t;
        float v = x[i];
        unsigned short h = bf_rne(v);
        float hf = __uint_as_float(((unsigned int)h) << 16);
        xhi[i] = h;
        xlo[i] = bf_rne(v - hf);
    } else if (bid < 1280) {               // fpack: 65536 elems
        int idx = (bid - 1024) * 256 + t;
        int e = idx & 7, lane = (idx >> 3) & 63, step = (idx >> 9) & 31, mt = idx >> 14;
        int row = mt * 32 + (lane & 31);
        int k = step * 16 + (lane >> 5) * 8 + e;
        float v = F[row * 512 + k];
        unsigned short h = bf_rne(v);
        float hf = __uint_as_float(((unsigned int)h) << 16);
        Fph[idx] = h;
        Fpl[idx] = bf_rne(v - hf);
    } else {                               // pos + ham
        if (t < 128) {
            double p = (double)((float)(-1.0 + 2.0 * (double)t / 127.0));
            posT[t * 33 + 0] = (float)p;
            for (int i = 0; i < 16; ++i) {
                double a = ldexp(p, i) * PI_D;
                posT[t * 33 + 1 + 2 * i] = (float)sin(a);
                posT[t * 33 + 2 + 2 * i] = (float)cos(a);
            }
        }
#pragma unroll
        for (int i = 0; i < 2; ++i) {
            int w = t + i * 256;
            ham[w] = (float)(0.54 - 0.46 * cos(2.0 * PI_D * (double)w / 511.0));
        }
    }
}

// ---------------- conv + abs + pool: 2 chunks (512 samples) per block ----------------
__global__ void __launch_bounds__(512) conv_mfma_k(
        const unsigned short* __restrict__ xhi, const unsigned short* __restrict__ xlo,
        const unsigned short* __restrict__ Fph, const unsigned short* __restrict__ Fpl,
        float* __restrict__ P) {
    int cp = blockIdx.x, b = blockIdx.y;   // cp in [0,64): chunks 2cp, 2cp+1
    int t = threadIdx.x;
    __shared__ __align__(16) unsigned short xsh[8][1032];
    __shared__ __align__(16) unsigned short xsl[8][1032];
    __shared__ float Pp[2][128];
    int base = cp * 512 - 256;
    for (int j = t; j < 1024; j += 512) {
        int gi = base + j;
        unsigned short h = 0, l = 0;
        if (gi >= 0 && gi < NS) { h = xhi[b * NS + gi]; l = xlo[b * NS + gi]; }
#pragma unroll
        for (int r = 0; r < 8; ++r) {
            int slot = j - r;
            if (slot >= 0) { xsh[r][slot] = h; xsl[r][slot] = l; }
        }
    }
    if (t < 256) Pp[t >> 7][t & 127] = 0.f;
    __syncthreads();

    int wid = t >> 6, lane = t & 63;
    int col = lane & 31, g = lane >> 5;
    int mbase = (wid & 1) * 64;
    int nbase = (wid >> 1) * 64;
    int rsel = col & 7;
    int p0 = nbase + col + 8 * g - rsel;
    int mt0 = (wid & 1) * 2;
    const unsigned short* aph = Fph + (size_t)mt0 * 16384 + lane * 8;
    const unsigned short* apl = Fpl + (size_t)mt0 * 16384 + lane * 8;

#pragma unroll
    for (int chunk = 0; chunk < 2; ++chunk) {
        const bfrag* bh0 = (const bfrag*)&xsh[rsel][p0 + chunk * 256];
        const bfrag* bl0 = (const bfrag*)&xsl[rsel][p0 + chunk * 256];
        const bfrag* bh1 = (const bfrag*)&xsh[rsel][p0 + chunk * 256 + 32];
        const bfrag* bl1 = (const bfrag*)&xsl[rsel][p0 + chunk * 256 + 32];

        f32x16 c00, c01, c10, c11;
#pragma unroll
        for (int r = 0; r < 16; ++r) { c00[r] = 0.f; c01[r] = 0.f; c10[r] = 0.f; c11[r] = 0.f; }

        bfrag ch0 = *(const bfrag*)(aph);
        bfrag ch1 = *(const bfrag*)(aph + 16384);
        bfrag cl0 = *(const bfrag*)(apl);
        bfrag cl1 = *(const bfrag*)(apl + 16384);
        bfrag dh0 = bh0[0], dl0 = bl0[0], dh1 = bh1[0], dl1 = bl1[0];
#pragma unroll 2
        for (int step = 0; step < 32; ++step) {
            int sn = (step < 31) ? step + 1 : 31;
            bfrag nh0 = *(const bfrag*)(aph + sn * 512);
            bfrag nh1 = *(const bfrag*)(aph + 16384 + sn * 512);
            bfrag nl0 = *(const bfrag*)(apl + sn * 512);
            bfrag nl1 = *(const bfrag*)(apl + 16384 + sn * 512);
            bfrag mh0 = bh0[2 * sn], ml0 = bl0[2 * sn];
            bfrag mh1 = bh1[2 * sn], ml1 = bl1[2 * sn];
            c00 = __builtin_amdgcn_mfma_f32_32x32x16_bf16(ch0, dh0, c00, 0, 0, 0);
            c00 = __builtin_amdgcn_mfma_f32_32x32x16_bf16(ch0, dl0, c00, 0, 0, 0);
            c00 = __builtin_amdgcn_mfma_f32_32x32x16_bf16(cl0, dh0, c00, 0, 0, 0);
            c01 = __builtin_amdgcn_mfma_f32_32x32x16_bf16(ch0, dh1, c01, 0, 0, 0);
            c01 = __builtin_amdgcn_mfma_f32_32x32x16_bf16(ch0, dl1, c01, 0, 0, 0);
            c01 = __builtin_amdgcn_mfma_f32_32x32x16_bf16(cl0, dh1, c01, 0, 0, 0);
            c10 = __builtin_amdgcn_mfma_f32_32x32x16_bf16(ch1, dh0, c10, 0, 0, 0);
            c10 = __builtin_amdgcn_mfma_f32_32x32x16_bf16(ch1, dl0, c10, 0, 0, 0);
            c10 = __builtin_amdgcn_mfma_f32_32x32x16_bf16(cl1, dh0, c10, 0, 0, 0);
            c11 = __builtin_amdgcn_mfma_f32_32x32x16_bf16(ch1, dh1, c11, 0, 0, 0);
            c11 = __builtin_amdgcn_mfma_f32_32x32x16_bf16(ch1, dl1, c11, 0, 0, 0);
            c11 = __builtin_amdgcn_mfma_f32_32x32x16_bf16(cl1, dh1, c11, 0, 0, 0);
            ch0 = nh0; ch1 = nh1; cl0 = nl0; cl1 = nl1;
            dh0 = mh0; dl0 = ml0; dh1 = mh1; dl1 = ml1;
        }

#pragma unroll
        for (int r = 0; r < 16; ++r) {
            float s0 = fabsf(c00[r]) + fabsf(c01[r]);
            float s1 = fabsf(c10[r]) + fabsf(c11[r]);
#pragma unroll
            for (int m = 1; m <= 16; m <<= 1) { s0 += __shfl_xor(s0, m); s1 += __shfl_xor(s1, m); }
            if ((lane & 31) == 0) {
                int rowoff = (r & 3) + 8 * (r >> 2) + 4 * g;
                atomicAdd(&Pp[chunk][mbase + rowoff], s0);
                atomicAdd(&Pp[chunk][mbase + 32 + rowoff], s1);
            }
        }
    }
    __syncthreads();
    if (t < 256) P[((size_t)b * 128 + (t & 127)) * 128 + cp * 2 + (t >> 7)] = Pp[t >> 7][t & 127];
}

// ---------------- weight packing: W[N][K] -> [ct][kt][64] float4 ----------------
struct PackPtrs { const float* p[51]; };

__global__ void pack_k(PackPtrs pp, float4* __restrict__ dst) {
    int m = blockIdx.y;
    const float* src = pp.p[m];
    int N, K, KT; size_t off;
    if (m < 12)      { N = 384; K = 128; KT = 32; off = (size_t)m * 12288; }
    else if (m < 24) { N = 128; K = 128; KT = 32; off = 147456 + (size_t)(m - 12) * 4096; }
    else if (m < 36) { N = 128; K = 128; KT = 32; off = 196608 + (size_t)(m - 24) * 4096; }
    else if (m < 48) { N = 128; K = 128; KT = 32; off = 245760 + (size_t)(m - 36) * 4096; }
    else if (m == 48){ N = 128; K = 161; KT = 41; off = 294912; }
    else if (m == 49){ N = 128; K = 161; KT = 41; off = 300160; }
    else             { N = 512; K = 128; KT = 32; off = 305408; }
    int idx = blockIdx.x * 256 + threadIdx.x;
    int total = (N >> 6) * KT * 64;
    if (idx >= total) return;
    int ln = idx & 63;
    int kt = (idx >> 6) % KT;
    int ct = idx / (KT * 64);
    int cc = ct * 64 + ln;
    int k0 = kt * 4;
    float4 v;
    v.x = (k0 + 0 < K) ? src[(size_t)cc * K + k0 + 0] : 0.f;
    v.y = (k0 + 1 < K) ? src[(size_t)cc * K + k0 + 1] : 0.f;
    v.z = (k0 + 2 < K) ? src[(size_t)cc * K + k0 + 2] : 0.f;
    v.w = (k0 + 3 < K) ? src[(size_t)cc * K + k0 + 3] : 0.f;
    dst[off + idx] = v;
}

// ---------------- megakernel (round-13 structure: K-split GEMM + fused reduces) ----------------
struct MegaArgs {
    const float* b_qkv[12]; const float* b_o[12]; const float* b1[12]; const float* b2[12];
    const float* ln1g[12]; const float* ln1b[12]; const float* ln2g[12]; const float* ln2b[12];
    const float* embed_b; const float* embed2_b; const float* env_w; const float* env_b;
    const float* samp_b;
    const float* posT; const float* ham; const float* P;
    const float4* Wp;
    float* KV;    // 2 parities x 1024 rows x 256 (K|V)
    float* envbuf; float* Y; float* out;
    unsigned* ctr;
};

struct __align__(16) SM {
    float KV[128][129];   // attention staging; ALSO reused as partial buffer in qkv/samp tails
    union { float S[16][128]; float partial[16][128]; };
    float Aq[4][128];
    float Ax[4][128];
    float Ax2[4][128];
    float Ah[4][128];
    float cv[4][176];
    float red2[16];
    int   red2i[8];
    float tvals[128], tout[128], Linv[16];
};

__device__ __forceinline__ void gbarb(unsigned* ctr, unsigned& bi) {
    asm volatile("s_waitcnt vmcnt(0)" ::: "memory");
    __syncthreads();
    if (threadIdx.x == 0) {
        bi += 1;
        __hip_atomic_fetch_add(ctr, 1u, __ATOMIC_RELAXED, __HIP_MEMORY_SCOPE_AGENT);
        unsigned target = bi * 32u;
        while (__hip_atomic_load(ctr, __ATOMIC_RELAXED, __HIP_MEMORY_SCOPE_AGENT) < target) {
            __builtin_amdgcn_s_sleep(1);
        }
    }
    __syncthreads();
}

template <int NCB>
__device__ __forceinline__ void gemm_acc(const float* A, int astride, const float4* Wp,
                                         int KT, int t, float (*acc)[4]) {
    int cidx = t & 127, kq = t >> 7;
    int KTq = (KT + 3) >> 2;
    int kt0 = kq * KTq;
    int kt1 = kt0 + KTq; if (kt1 > KT) kt1 = KT;
#pragma unroll
    for (int i = 0; i < NCB; ++i) { acc[i][0] = 0.f; acc[i][1] = 0.f; acc[i][2] = 0.f; acc[i][3] = 0.f; }
    for (int kt = kt0; kt < kt1; ++kt) {
        float4 a0 = *(const float4*)(A + 0 * astride + kt * 4);
        float4 a1 = *(const float4*)(A + 1 * astride + kt * 4);
        float4 a2 = *(const float4*)(A + 2 * astride + kt * 4);
        float4 a3 = *(const float4*)(A + 3 * astride + kt * 4);
#pragma unroll
        for (int i = 0; i < NCB; ++i) {
            int cb = cidx + i * 128;
            float4 w = Wp[((size_t)((cb >> 6) * KT + kt)) * 64 + (cb & 63)];
            acc[i][0] += a0.x * w.x + a0.y * w.y + a0.z * w.z + a0.w * w.w;
            acc[i][1] += a1.x * w.x + a1.y * w.y + a1.z * w.z + a1.w * w.w;
            acc[i][2] += a2.x * w.x + a2.y * w.y + a2.z * w.z + a2.w * w.w;
            acc[i][3] += a3.x * w.x + a3.y * w.y + a3.z * w.z + a3.w * w.w;
        }
    }
}

__device__ __forceinline__ float gemm_reduce(const float* a4, int t, SM& sm) {
    int cidx = t & 127, kq = t >> 7;
    __syncthreads();
#pragma unroll
    for (int r = 0; r < 4; ++r) sm.partial[r * 4 + kq][cidx] = a4[r];
    __syncthreads();
    int rsel = t >> 7;
    return sm.partial[rsel * 4 + 0][cidx] + sm.partial[rsel * 4 + 1][cidx]
         + sm.partial[rsel * 4 + 2][cidx] + sm.partial[rsel * 4 + 3][cidx];
}

// lnorm with NO trailing barrier (red2's next writer is >=2 barriers away in all call sites)
__device__ __forceinline__ float lnorm(float v, int t, const float* g, const float* be, SM& sm) {
    float s = v, s2 = v * v;
#pragma unroll
    for (int mm = 1; mm <= 32; mm <<= 1) { s += __shfl_xor(s, mm); s2 += __shfl_xor(s2, mm); }
    int w = t >> 6;
    if ((t & 63) == 0) { sm.red2[w * 2] = s; sm.red2[w * 2 + 1] = s2; }
    __syncthreads();
    int r = t >> 7;
    float S = sm.red2[(2 * r) * 2] + sm.red2[(2 * r + 1) * 2];
    float S2 = sm.red2[(2 * r) * 2 + 1] + sm.red2[(2 * r + 1) * 2 + 1];
    float mu = S * (1.f / 128.f);
    float var = S2 * (1.f / 128.f) - mu * mu;
    return (v - mu) * rsqrtf(var + 1e-5f) * g[t & 127] + be[t & 127];
}

// qkv: fused single-barrier reduce, partials aliased into dead KV LDS region
__device__ __forceinline__ void qkv_tail(const MegaArgs& a, SM& sm, int l, int t, int rowbase) {
    const float4* qkvp = a.Wp + (size_t)l * 12288;
    float acc3[3][4];
    gemm_acc<3>(&sm.Ax[0][0], 128, qkvp, 32, t, acc3);
    int c = t & 127, kq = t >> 7;
    float* part = &sm.KV[0][0];    // 48x128 floats, KV staging is dead here
#pragma unroll
    for (int i = 0; i < 3; ++i)
#pragma unroll
        for (int r = 0; r < 4; ++r)
            part[((i * 4 + r) * 4 + kq) * 128 + c] = acc3[i][r];
    __syncthreads();
    int r = kq;
    const float* bq = a.b_qkv[l];
    float* KVp = a.KV + (size_t)(l & 1) * 262144;
    float vq = 0.f, vk = 0.f, vv = 0.f;
#pragma unroll
    for (int q = 0; q < 4; ++q) {
        vq += part[((0 * 4 + r) * 4 + q) * 128 + c];
        vk += part[((1 * 4 + r) * 4 + q) * 128 + c];
        vv += part[((2 * 4 + r) * 4 + q) * 128 + c];
    }
    sm.Aq[r][c] = vq + bq[c];
    ASTORE(&KVp[(size_t)(rowbase + r) * 256 + c], vk + bq[128 + c]);
    ASTORE(&KVp[(size_t)(rowbase + r) * 256 + 128 + c], vv + bq[256 + c]);
}

__global__ void __launch_bounds__(512, 1) mega_k(MegaArgs a) {
    __shared__ SM sm;
    const int t = threadIdx.x;
    const int bid = blockIdx.x;
    const int rowbase = bid * 4;
    const int b = rowbase >> 7;
    const int tfr = rowbase & 127;
    const int c = t & 127;
    const int rs = t >> 7;
    unsigned bctr = 0;
    unsigned* myctr = a.ctr + b * 16;

    const float4* embedp  = a.Wp + 294912;
    const float4* embed2p = a.Wp + 300160;
    const float4* sampp   = a.Wp + 305408;

    // ---- prologue: embed + qkv layer0 ----
    {
        int tf = tfr + rs;
        for (int j = c; j < 176; j += 128) {
            float val = 0.f;
            if (j < 33) val = a.posT[tf * 33 + j];
            else if (j < 161) {
                int o = j - 33;
                float p1 = a.P[((size_t)(b * 128 + o)) * 128 + tf];
                float p0 = (tf > 0) ? a.P[((size_t)(b * 128 + o)) * 128 + tf - 1] : 0.f;
                val = (p0 + p1) * (1.f / 512.f);
            }
            sm.cv[rs][j] = val;
        }
        __syncthreads();
        float acc1[1][4];
        gemm_acc<1>(&sm.cv[0][0], 176, embedp, 41, t, acc1);
        float v = gemm_reduce(acc1[0], t, sm) + a.embed_b[c];
        sm.Ax[rs][c] = v;
        __syncthreads();
        qkv_tail(a, sm, 0, t, rowbase);
        gbarb(myctr, bctr);
    }

    for (int l = 0; l < 12; ++l) {
        if (l == 6) {
            // ---- mid: env softmax + top16 + embed2 + qkv dec0 ----
            float v = (t < 128) ? ALOAD(&a.envbuf[b * 128 + t]) : -1e30f;
            float m_ = v;
#pragma unroll
            for (int mm = 1; mm <= 32; mm <<= 1) m_ = fmaxf(m_, __shfl_xor(m_, mm));
            if ((t & 63) == 0) sm.red2[(t >> 6) * 2] = m_;
            __syncthreads();
            float mx = fmaxf(sm.red2[0], sm.red2[2]);
            float e = (t < 128) ? expf(v - mx) : 0.f;
            float ssum = e;
#pragma unroll
            for (int mm = 1; mm <= 32; mm <<= 1) ssum += __shfl_xor(ssum, mm);
            __syncthreads();
            if ((t & 63) == 0) sm.red2[(t >> 6) * 2 + 1] = ssum;
            __syncthreads();
            float lsum = sm.red2[1] + sm.red2[3];
            if (t < 128) { sm.tvals[t] = e / lsum; sm.tout[t] = 0.f; }
            __syncthreads();
            for (int it = 0; it < 16; ++it) {
                float cv_ = (t < 128) ? sm.tvals[t] : -2.f;
                int ci = t & 127;
#pragma unroll
                for (int mm = 1; mm <= 32; mm <<= 1) {
                    float ov = __shfl_xor(cv_, mm);
                    int oi = __shfl_xor(ci, mm);
                    if (ov > cv_ || (ov == cv_ && oi < ci)) { cv_ = ov; ci = oi; }
                }
                if ((t & 63) == 0) { sm.red2[(t >> 6) * 2] = cv_; sm.red2i[t >> 6] = ci; }
                __syncthreads();
                if (t == 0) {
                    float v0 = sm.red2[0], v1 = sm.red2[2];
                    int i0 = sm.red2i[0], i1 = sm.red2i[1];
                    float bv; int bi2;
                    if (v1 > v0 || (v1 == v0 && i1 < i0)) { bv = v1; bi2 = i1; }
                    else { bv = v0; bi2 = i0; }
                    sm.tout[bi2] = bv;
                    sm.tvals[bi2] = -3.f;
                }
                __syncthreads();
            }
            float sclr = sm.tout[tfr + rs];
            for (int j = c; j < 176; j += 128) {
                float val = 0.f;
                if (j < 33) val = a.posT[(tfr + rs) * 33 + j];
                else if (j < 161) val = sm.Ax[rs][j - 33] * sclr;
                sm.cv[rs][j] = val;
            }
            __syncthreads();
            float acc1[1][4];
            gemm_acc<1>(&sm.cv[0][0], 176, embed2p, 41, t, acc1);
            float vv = gemm_reduce(acc1[0], t, sm) + a.embed2_b[c];
            sm.Ax[rs][c] = vv;
            __syncthreads();
            qkv_tail(a, sm, 6, t, rowbase);
            gbarb(myctr, bctr);
        }

        const float4* op  = a.Wp + 147456 + (size_t)l * 4096;
        const float4* w1p = a.Wp + 196608 + (size_t)l * 4096;
        const float4* w2p = a.Wp + 245760 + (size_t)l * 4096;
        const float* KVg = a.KV + (size_t)(l & 1) * 262144 + (size_t)b * 32768;

        // ---- A: attention (coalesced device-coherent loads -> LDS transpose) ----
        {
            float kst[32], vst[32];
#pragma unroll
            for (int j = 0; j < 32; ++j) {
                int f = j * 512 + t;
                kst[j] = ALOAD(&KVg[(size_t)(f >> 7) * 256 + (f & 127)]);
            }
#pragma unroll
            for (int j = 0; j < 32; ++j) {
                int f = j * 512 + t;
                vst[j] = ALOAD(&KVg[(size_t)(f >> 7) * 256 + 128 + (f & 127)]);
            }
            int cd = t & 127, r0 = t >> 7;
#pragma unroll
            for (int j = 0; j < 32; ++j) sm.KV[cd][j * 4 + r0] = kst[j];
            __syncthreads();
            {   // QK^T
                int h = t >> 7, k = c;
                float s0 = 0.f, s1 = 0.f, s2 = 0.f, s3 = 0.f;
#pragma unroll
                for (int d = 0; d < 32; ++d) {
                    float kvv = sm.KV[h * 32 + d][k];
                    s0 += sm.Aq[0][h * 32 + d] * kvv;
                    s1 += sm.Aq[1][h * 32 + d] * kvv;
                    s2 += sm.Aq[2][h * 32 + d] * kvv;
                    s3 += sm.Aq[3][h * 32 + d] * kvv;
                }
                const float scl = 0.17677669529663687f;
                sm.S[h * 4 + 0][k] = s0 * scl;
                sm.S[h * 4 + 1][k] = s1 * scl;
                sm.S[h * 4 + 2][k] = s2 * scl;
                sm.S[h * 4 + 3][k] = s3 * scl;
            }
            __syncthreads();
#pragma unroll
            for (int j = 0; j < 32; ++j) sm.KV[cd][j * 4 + r0] = vst[j];
            {   // softmax
                int row = t >> 5, l32 = t & 31;
                float v0 = sm.S[row][l32], v1 = sm.S[row][l32 + 32];
                float v2 = sm.S[row][l32 + 64], v3 = sm.S[row][l32 + 96];
                float mx = fmaxf(fmaxf(v0, v1), fmaxf(v2, v3));
#pragma unroll
                for (int mm = 1; mm <= 16; mm <<= 1) mx = fmaxf(mx, __shfl_xor(mx, mm));
                float e0 = __expf(v0 - mx), e1 = __expf(v1 - mx);
                float e2 = __expf(v2 - mx), e3 = __expf(v3 - mx);
                float ls = e0 + e1 + e2 + e3;
#pragma unroll
                for (int mm = 1; mm <= 16; mm <<= 1) ls += __shfl_xor(ls, mm);
                sm.S[row][l32] = e0; sm.S[row][l32 + 32] = e1;
                sm.S[row][l32 + 64] = e2; sm.S[row][l32 + 96] = e3;
                if (l32 == 0) sm.Linv[row] = 1.f / ls;
            }
            __syncthreads();
            {   // PV
                int h = t >> 7, r = (t >> 5) & 3, d = t & 31;
                const float* Pr = &sm.S[h * 4 + r][0];
                float o = 0.f;
#pragma unroll 8
                for (int k2 = 0; k2 < 128; ++k2) o += Pr[k2] * sm.KV[h * 32 + d][k2];
                sm.Ah[r][h * 32 + d] = o * sm.Linv[h * 4 + r];
            }
            __syncthreads();
        }
        // ---- D: o-proj + residual + ln1 ----
        {
            float acc1[1][4];
            gemm_acc<1>(&sm.Ah[0][0], 128, op, 32, t, acc1);
            float v = gemm_reduce(acc1[0], t, sm);
            v += a.b_o[l][c] + sm.Ax[rs][c];
            v = lnorm(v, t, a.ln1g[l], a.ln1b[l], sm);
            sm.Ax2[rs][c] = v;
            __syncthreads();
        }
        // ---- E/F: ffn + residual + ln2 ----
        {
            float acc1[1][4];
            gemm_acc<1>(&sm.Ax2[0][0], 128, w1p, 32, t, acc1);
            float v = fmaxf(gemm_reduce(acc1[0], t, sm) + a.b1[l][c], 0.f);
            sm.Ah[rs][c] = v;
            __syncthreads();
            float acc2[1][4];
            gemm_acc<1>(&sm.Ah[0][0], 128, w2p, 32, t, acc2);
            float v2 = gemm_reduce(acc2[0], t, sm) + a.b2[l][c] + sm.Ax2[rs][c];
            v2 = lnorm(v2, t, a.ln2g[l], a.ln2b[l], sm);
            sm.Ax[rs][c] = v2;
            __syncthreads();
        }
        // ---- G: tail ----
        if (l == 5) {
            float pv = sm.Ax[rs][c] * a.env_w[c];
#pragma unroll
            for (int mm = 1; mm <= 32; mm <<= 1) pv += __shfl_xor(pv, mm);
            int w = t >> 6;
            if ((t & 63) == 0) sm.red2[w * 2] = pv;
            __syncthreads();
            if (t < 4) ASTORE(&a.envbuf[rowbase + t],
                              sm.red2[(2 * t) * 2] + sm.red2[(2 * t + 1) * 2] + a.env_b[0]);
            __syncthreads();
        } else if (l == 11) {
            // samp: fused single-barrier 4-output reduce in dead KV region
            float acc4[4][4];
            gemm_acc<4>(&sm.Ax[0][0], 128, sampp, 32, t, acc4);
            float* part = &sm.KV[0][0];   // 64x128 floats
            int kq = rs;
#pragma unroll
            for (int i = 0; i < 4; ++i)
#pragma unroll
                for (int r = 0; r < 4; ++r)
                    part[((i * 4 + r) * 4 + kq) * 128 + c] = acc4[i][r];
            __syncthreads();
#pragma unroll
            for (int i = 0; i < 4; ++i) {
                float v = 0.f;
#pragma unroll
                for (int q = 0; q < 4; ++q) v += part[((i * 4 + rs) * 4 + q) * 128 + c];
                int cg = c + i * 128;
                v = (v + a.samp_b[cg]) * a.ham[cg];
                ASTORE(&a.Y[((size_t)(rowbase + rs)) * 512 + cg], v);
            }
        } else {
            qkv_tail(a, sm, l + 1, t, rowbase);
        }
        gbarb(myctr, bctr);
    }

    // ---- overlap-add (batch-local) ----
    {
        int b32 = bid & 31;
#pragma unroll
        for (int i = 0; i < 2; ++i) {
            int il = b32 * 512 + t + i * 16384;
            int t0 = il >> 8, w0 = il & 255;
            float acc = ALOAD(&a.Y[((size_t)(b * 128 + t0)) * 512 + w0]);
            if (t0 > 0) acc += ALOAD(&a.Y[((size_t)(b * 128 + t0 - 1)) * 512 + w0 + 256]);
            a.out[(size_t)b * 32768 + il] = acc;
        }
    }
}

extern "C" void kernel_launch(void* const* d_in, const int* in_sizes, int n_in,
                              void* d_out, int out_size, void* d_ws, size_t ws_size,
                              hipStream_t stream) {
    const float* x        = (const float*)d_in[0];
    const float* filters  = (const float*)d_in[1];
    const float* embed_w  = (const float*)d_in[2];
    const float* embed_b  = (const float*)d_in[3];
    const float* embed2_w = (const float*)d_in[4];
    const float* embed2_b = (const float*)d_in[5];
    const float* env_w    = (const float*)d_in[6];
    const float* env_b    = (const float*)d_in[7];
    const float* samp_w   = (const float*)d_in[8];
    const float* samp_b   = (const float*)d_in[9];

    float* ws = (float*)d_ws;
    float* P     = ws;                      // 131072
    float* posT  = ws + 131072;             // 4352
    float* hamw  = ws + 135424;             // 512
    float* envb  = ws + 135936;             // 1024
    float* KV    = ws + 136960;             // 524288 (2 parities x 1024 x 256)
    float* Y     = ws + 661248;             // 524288
    float4* Wp   = (float4*)(ws + 1185536); // 321792 float4
    unsigned* ctr = (unsigned*)(ws + 2472704);
    // conv-prep aliases (dead regions at conv time)
    unsigned short* xhi = (unsigned short*)Y;
    unsigned short* xlo = (unsigned short*)(Y + 131072);
    unsigned short* Fph = (unsigned short*)KV;
    unsigned short* Fpl = (unsigned short*)(KV + 32768);

    prep_k<<<1281, 256, 0, stream>>>(x, filters, xhi, xlo, Fph, Fpl, posT, hamw);
    conv_mfma_k<<<dim3(64, 8), 512, 0, stream>>>(xhi, xlo, Fph, Fpl, P);

    PackPtrs pp;
    for (int l = 0; l < 12; ++l) {
        int base = (l < 6) ? 10 + l * 12 : 82 + (l - 6) * 12;
        pp.p[l]      = (const float*)d_in[base + 0];
        pp.p[12 + l] = (const float*)d_in[base + 2];
        pp.p[24 + l] = (const float*)d_in[base + 4];
        pp.p[36 + l] = (const float*)d_in[base + 6];
    }
    pp.p[48] = embed_w; pp.p[49] = embed2_w; pp.p[50] = samp_w;
    pack_k<<<dim3(64, 51), 256, 0, stream>>>(pp, Wp);

    hipMemsetAsync(ctr, 0, 1024, stream);

    MegaArgs ma;
    for (int l = 0; l < 12; ++l) {
        int base = (l < 6) ? 10 + l * 12 : 82 + (l - 6) * 12;
        ma.b_qkv[l] = (const float*)d_in[base + 1];
        ma.b_o[l]   = (const float*)d_in[base + 3];
        ma.b1[l]    = (const float*)d_in[base + 5];
        ma.b2[l]    = (const float*)d_in[base + 7];
        ma.ln1g[l]  = (const float*)d_in[base + 8];
        ma.ln1b[l]  = (const float*)d_in[base + 9];
        ma.ln2g[l]  = (const float*)d_in[base + 10];
        ma.ln2b[l]  = (const float*)d_in[base + 11];
    }
    ma.embed_b = embed_b; ma.embed2_b = embed2_b;
    ma.env_w = env_w; ma.env_b = env_b; ma.samp_b = samp_b;
    ma.posT = posT; ma.ham = hamw; ma.P = P;
    ma.Wp = (const float4*)Wp;
    ma.KV = KV; ma.envbuf = envb; ma.Y = Y; ma.out = (float*)d_out;
    ma.ctr = ctr;

    mega_k<<<256, 512, 0, stream>>>(ma);
}

// Round 16
// 333.154 us; speedup vs baseline: 1.2974x; 1.0263x over previous
//
#include <hip/hip_runtime.h>
#include <math.h>

#define NB 8
#define NS 32768
#define SEQ 128
#define DIM 128
#define KER 512
#define PI_D 3.14159265358979323846

#define ALOAD(p)     __hip_atomic_load((p), __ATOMIC_RELAXED, __HIP_MEMORY_SCOPE_AGENT)
#define ASTORE(p, v) __hip_atomic_store((p), (v), __ATOMIC_RELAXED, __HIP_MEMORY_SCOPE_AGENT)

typedef __attribute__((ext_vector_type(8))) short bfrag;
typedef __attribute__((ext_vector_type(16))) float f32x16;

__device__ __forceinline__ unsigned short bf_rne(float v) {
    unsigned int u = __float_as_uint(v);
    unsigned int r = u + 0x7FFFu + ((u >> 16) & 1u);
    return (unsigned short)(r >> 16);
}

// ---- fused prep: bfsplit(x) | fpack(filters) | pos+ham+ctr | weight pack ----
struct PackPtrs { const float* p[51]; };

__global__ void prep_k(const float* __restrict__ x, const float* __restrict__ F,
                       unsigned short* __restrict__ xhi, unsigned short* __restrict__ xlo,
                       unsigned short* __restrict__ Fph, unsigned short* __restrict__ Fpl,
                       float* __restrict__ posT, float* __restrict__ ham,
                       PackPtrs pp, float4* __restrict__ dst, unsigned* __restrict__ ctr) {
    int bid = blockIdx.x, t = threadIdx.x;
    if (bid < 1024) {                      // bfsplit of x: 262144 elems
        int i = bid * 256 + t;
        float v = x[i];
        unsigned short h = bf_rne(v);
        float hf = __uint_as_float(((unsigned int)h) << 16);
        xhi[i] = h;
        xlo[i] = bf_rne(v - hf);
    } else if (bid < 1280) {               // fpack: 65536 elems
        int idx = (bid - 1024) * 256 + t;
        int e = idx & 7, lane = (idx >> 3) & 63, step = (idx >> 9) & 31, mt = idx >> 14;
        int row = mt * 32 + (lane & 31);
        int k = step * 16 + (lane >> 5) * 8 + e;
        float v = F[row * 512 + k];
        unsigned short h = bf_rne(v);
        float hf = __uint_as_float(((unsigned int)h) << 16);
        Fph[idx] = h;
        Fpl[idx] = bf_rne(v - hf);
    } else if (bid == 1280) {              // pos + ham + ctr zero
        if (t < 128) {
            double p = (double)((float)(-1.0 + 2.0 * (double)t / 127.0));
            posT[t * 33 + 0] = (float)p;
            for (int i = 0; i < 16; ++i) {
                double a = ldexp(p, i) * PI_D;
                posT[t * 33 + 1 + 2 * i] = (float)sin(a);
                posT[t * 33 + 2 + 2 * i] = (float)cos(a);
            }
        }
#pragma unroll
        for (int i = 0; i < 2; ++i) {
            int w = t + i * 256;
            ham[w] = (float)(0.54 - 0.46 * cos(2.0 * PI_D * (double)w / 511.0));
        }
        ctr[t] = 0u;
    } else {                               // weight pack: 51 matrices x 64 blocks
        int pb = bid - 1281;
        int m = pb >> 6;
        const float* src = pp.p[m];
        int N, K, KT; size_t off;
        if (m < 12)      { N = 384; K = 128; KT = 32; off = (size_t)m * 12288; }
        else if (m < 24) { N = 128; K = 128; KT = 32; off = 147456 + (size_t)(m - 12) * 4096; }
        else if (m < 36) { N = 128; K = 128; KT = 32; off = 196608 + (size_t)(m - 24) * 4096; }
        else if (m < 48) { N = 128; K = 128; KT = 32; off = 245760 + (size_t)(m - 36) * 4096; }
        else if (m == 48){ N = 128; K = 161; KT = 41; off = 294912; }
        else if (m == 49){ N = 128; K = 161; KT = 41; off = 300160; }
        else             { N = 512; K = 128; KT = 32; off = 305408; }
        int idx = (pb & 63) * 256 + t;
        int total = (N >> 6) * KT * 64;
        if (idx >= total) return;
        int ln = idx & 63;
        int kt = (idx >> 6) % KT;
        int ct = idx / (KT * 64);
        int cc = ct * 64 + ln;
        int k0 = kt * 4;
        float4 v;
        v.x = (k0 + 0 < K) ? src[(size_t)cc * K + k0 + 0] : 0.f;
        v.y = (k0 + 1 < K) ? src[(size_t)cc * K + k0 + 1] : 0.f;
        v.z = (k0 + 2 < K) ? src[(size_t)cc * K + k0 + 2] : 0.f;
        v.w = (k0 + 3 < K) ? src[(size_t)cc * K + k0 + 3] : 0.f;
        dst[off + idx] = v;
    }
}

// ---------------- conv + abs + pool: 2 chunks (512 samples) per block ----------------
__global__ void __launch_bounds__(512) conv_mfma_k(
        const unsigned short* __restrict__ xhi, const unsigned short* __restrict__ xlo,
        const unsigned short* __restrict__ Fph, const unsigned short* __restrict__ Fpl,
        float* __restrict__ P) {
    int cp = blockIdx.x, b = blockIdx.y;   // cp in [0,64): chunks 2cp, 2cp+1
    int t = threadIdx.x;
    __shared__ __align__(16) unsigned short xsh[8][1032];
    __shared__ __align__(16) unsigned short xsl[8][1032];
    __shared__ float Pp[2][128];
    int base = cp * 512 - 256;
    for (int j = t; j < 1024; j += 512) {
        int gi = base + j;
        unsigned short h = 0, l = 0;
        if (gi >= 0 && gi < NS) { h = xhi[b * NS + gi]; l = xlo[b * NS + gi]; }
#pragma unroll
        for (int r = 0; r < 8; ++r) {
            int slot = j - r;
            if (slot >= 0) { xsh[r][slot] = h; xsl[r][slot] = l; }
        }
    }
    if (t < 256) Pp[t >> 7][t & 127] = 0.f;
    __syncthreads();

    int wid = t >> 6, lane = t & 63;
    int col = lane & 31, g = lane >> 5;
    int mbase = (wid & 1) * 64;
    int nbase = (wid >> 1) * 64;
    int rsel = col & 7;
    int p0 = nbase + col + 8 * g - rsel;
    int mt0 = (wid & 1) * 2;
    const unsigned short* aph = Fph + (size_t)mt0 * 16384 + lane * 8;
    const unsigned short* apl = Fpl + (size_t)mt0 * 16384 + lane * 8;

#pragma unroll
    for (int chunk = 0; chunk < 2; ++chunk) {
        const bfrag* bh0 = (const bfrag*)&xsh[rsel][p0 + chunk * 256];
        const bfrag* bl0 = (const bfrag*)&xsl[rsel][p0 + chunk * 256];
        const bfrag* bh1 = (const bfrag*)&xsh[rsel][p0 + chunk * 256 + 32];
        const bfrag* bl1 = (const bfrag*)&xsl[rsel][p0 + chunk * 256 + 32];

        f32x16 c00, c01, c10, c11;
#pragma unroll
        for (int r = 0; r < 16; ++r) { c00[r] = 0.f; c01[r] = 0.f; c10[r] = 0.f; c11[r] = 0.f; }

        bfrag ch0 = *(const bfrag*)(aph);
        bfrag ch1 = *(const bfrag*)(aph + 16384);
        bfrag cl0 = *(const bfrag*)(apl);
        bfrag cl1 = *(const bfrag*)(apl + 16384);
        bfrag dh0 = bh0[0], dl0 = bl0[0], dh1 = bh1[0], dl1 = bl1[0];
#pragma unroll 2
        for (int step = 0; step < 32; ++step) {
            int sn = (step < 31) ? step + 1 : 31;
            bfrag nh0 = *(const bfrag*)(aph + sn * 512);
            bfrag nh1 = *(const bfrag*)(aph + 16384 + sn * 512);
            bfrag nl0 = *(const bfrag*)(apl + sn * 512);
            bfrag nl1 = *(const bfrag*)(apl + 16384 + sn * 512);
            bfrag mh0 = bh0[2 * sn], ml0 = bl0[2 * sn];
            bfrag mh1 = bh1[2 * sn], ml1 = bl1[2 * sn];
            c00 = __builtin_amdgcn_mfma_f32_32x32x16_bf16(ch0, dh0, c00, 0, 0, 0);
            c00 = __builtin_amdgcn_mfma_f32_32x32x16_bf16(ch0, dl0, c00, 0, 0, 0);
            c00 = __builtin_amdgcn_mfma_f32_32x32x16_bf16(cl0, dh0, c00, 0, 0, 0);
            c01 = __builtin_amdgcn_mfma_f32_32x32x16_bf16(ch0, dh1, c01, 0, 0, 0);
            c01 = __builtin_amdgcn_mfma_f32_32x32x16_bf16(ch0, dl1, c01, 0, 0, 0);
            c01 = __builtin_amdgcn_mfma_f32_32x32x16_bf16(cl0, dh1, c01, 0, 0, 0);
            c10 = __builtin_amdgcn_mfma_f32_32x32x16_bf16(ch1, dh0, c10, 0, 0, 0);
            c10 = __builtin_amdgcn_mfma_f32_32x32x16_bf16(ch1, dl0, c10, 0, 0, 0);
            c10 = __builtin_amdgcn_mfma_f32_32x32x16_bf16(cl1, dh0, c10, 0, 0, 0);
            c11 = __builtin_amdgcn_mfma_f32_32x32x16_bf16(ch1, dh1, c11, 0, 0, 0);
            c11 = __builtin_amdgcn_mfma_f32_32x32x16_bf16(ch1, dl1, c11, 0, 0, 0);
            c11 = __builtin_amdgcn_mfma_f32_32x32x16_bf16(cl1, dh1, c11, 0, 0, 0);
            ch0 = nh0; ch1 = nh1; cl0 = nl0; cl1 = nl1;
            dh0 = mh0; dl0 = ml0; dh1 = mh1; dl1 = ml1;
        }

#pragma unroll
        for (int r = 0; r < 16; ++r) {
            float s0 = fabsf(c00[r]) + fabsf(c01[r]);
            float s1 = fabsf(c10[r]) + fabsf(c11[r]);
#pragma unroll
            for (int m = 1; m <= 16; m <<= 1) { s0 += __shfl_xor(s0, m); s1 += __shfl_xor(s1, m); }
            if ((lane & 31) == 0) {
                int rowoff = (r & 3) + 8 * (r >> 2) + 4 * g;
                atomicAdd(&Pp[chunk][mbase + rowoff], s0);
                atomicAdd(&Pp[chunk][mbase + 32 + rowoff], s1);
            }
        }
    }
    __syncthreads();
    if (t < 256) P[((size_t)b * 128 + (t & 127)) * 128 + cp * 2 + (t >> 7)] = Pp[t >> 7][t & 127];
}

// ---------------- megakernel (round-13 structure: K-split GEMM + fused reduces) ----------------
struct MegaArgs {
    const float* b_qkv[12]; const float* b_o[12]; const float* b1[12]; const float* b2[12];
    const float* ln1g[12]; const float* ln1b[12]; const float* ln2g[12]; const float* ln2b[12];
    const float* embed_b; const float* embed2_b; const float* env_w; const float* env_b;
    const float* samp_b;
    const float* posT; const float* ham; const float* P;
    const float4* Wp;
    float* KV;    // 2 parities x 1024 rows x 256 (K|V)
    float* envbuf; float* Y; float* out;
    unsigned* ctr;
};

struct __align__(16) SM {
    float KV[128][129];   // attention staging; ALSO reused as partial buffer in qkv/samp tails
    union { float S[16][128]; float partial[16][128]; };
    float Aq[4][128];
    float Ax[4][128];
    float Ax2[4][128];
    float Ah[4][128];
    float cv[4][176];
    float red2[16];
    int   red2i[8];
    float tvals[128], tout[128], Linv[16];
};

__device__ __forceinline__ void gbarb(unsigned* ctr, unsigned& bi) {
    asm volatile("s_waitcnt vmcnt(0)" ::: "memory");
    __syncthreads();
    if (threadIdx.x == 0) {
        bi += 1;
        __hip_atomic_fetch_add(ctr, 1u, __ATOMIC_RELAXED, __HIP_MEMORY_SCOPE_AGENT);
        unsigned target = bi * 32u;
        while (__hip_atomic_load(ctr, __ATOMIC_RELAXED, __HIP_MEMORY_SCOPE_AGENT) < target) {
            __builtin_amdgcn_s_sleep(1);
        }
    }
    __syncthreads();
}

template <int NCB>
__device__ __forceinline__ void gemm_acc(const float* A, int astride, const float4* Wp,
                                         int KT, int t, float (*acc)[4]) {
    int cidx = t & 127, kq = t >> 7;
    int KTq = (KT + 3) >> 2;
    int kt0 = kq * KTq;
    int kt1 = kt0 + KTq; if (kt1 > KT) kt1 = KT;
#pragma unroll
    for (int i = 0; i < NCB; ++i) { acc[i][0] = 0.f; acc[i][1] = 0.f; acc[i][2] = 0.f; acc[i][3] = 0.f; }
    for (int kt = kt0; kt < kt1; ++kt) {
        float4 a0 = *(const float4*)(A + 0 * astride + kt * 4);
        float4 a1 = *(const float4*)(A + 1 * astride + kt * 4);
        float4 a2 = *(const float4*)(A + 2 * astride + kt * 4);
        float4 a3 = *(const float4*)(A + 3 * astride + kt * 4);
#pragma unroll
        for (int i = 0; i < NCB; ++i) {
            int cb = cidx + i * 128;
            float4 w = Wp[((size_t)((cb >> 6) * KT + kt)) * 64 + (cb & 63)];
            acc[i][0] += a0.x * w.x + a0.y * w.y + a0.z * w.z + a0.w * w.w;
            acc[i][1] += a1.x * w.x + a1.y * w.y + a1.z * w.z + a1.w * w.w;
            acc[i][2] += a2.x * w.x + a2.y * w.y + a2.z * w.z + a2.w * w.w;
            acc[i][3] += a3.x * w.x + a3.y * w.y + a3.z * w.z + a3.w * w.w;
        }
    }
}

__device__ __forceinline__ float gemm_reduce(const float* a4, int t, SM& sm) {
    int cidx = t & 127, kq = t >> 7;
    __syncthreads();
#pragma unroll
    for (int r = 0; r < 4; ++r) sm.partial[r * 4 + kq][cidx] = a4[r];
    __syncthreads();
    int rsel = t >> 7;
    return sm.partial[rsel * 4 + 0][cidx] + sm.partial[rsel * 4 + 1][cidx]
         + sm.partial[rsel * 4 + 2][cidx] + sm.partial[rsel * 4 + 3][cidx];
}

// lnorm with NO trailing barrier (red2's next writer is >=2 barriers away in all call sites)
__device__ __forceinline__ float lnorm(float v, int t, const float* g, const float* be, SM& sm) {
    float s = v, s2 = v * v;
#pragma unroll
    for (int mm = 1; mm <= 32; mm <<= 1) { s += __shfl_xor(s, mm); s2 += __shfl_xor(s2, mm); }
    int w = t >> 6;
    if ((t & 63) == 0) { sm.red2[w * 2] = s; sm.red2[w * 2 + 1] = s2; }
    __syncthreads();
    int r = t >> 7;
    float S = sm.red2[(2 * r) * 2] + sm.red2[(2 * r + 1) * 2];
    float S2 = sm.red2[(2 * r) * 2 + 1] + sm.red2[(2 * r + 1) * 2 + 1];
    float mu = S * (1.f / 128.f);
    float var = S2 * (1.f / 128.f) - mu * mu;
    return (v - mu) * rsqrtf(var + 1e-5f) * g[t & 127] + be[t & 127];
}

// qkv: fused single-barrier reduce, partials aliased into dead KV LDS region
__device__ __forceinline__ void qkv_tail(const MegaArgs& a, SM& sm, int l, int t, int rowbase) {
    const float4* qkvp = a.Wp + (size_t)l * 12288;
    float acc3[3][4];
    gemm_acc<3>(&sm.Ax[0][0], 128, qkvp, 32, t, acc3);
    int c = t & 127, kq = t >> 7;
    float* part = &sm.KV[0][0];    // 48x128 floats, KV staging is dead here
#pragma unroll
    for (int i = 0; i < 3; ++i)
#pragma unroll
        for (int r = 0; r < 4; ++r)
            part[((i * 4 + r) * 4 + kq) * 128 + c] = acc3[i][r];
    __syncthreads();
    int r = kq;
    const float* bq = a.b_qkv[l];
    float* KVp = a.KV + (size_t)(l & 1) * 262144;
    float vq = 0.f, vk = 0.f, vv = 0.f;
#pragma unroll
    for (int q = 0; q < 4; ++q) {
        vq += part[((0 * 4 + r) * 4 + q) * 128 + c];
        vk += part[((1 * 4 + r) * 4 + q) * 128 + c];
        vv += part[((2 * 4 + r) * 4 + q) * 128 + c];
    }
    sm.Aq[r][c] = vq + bq[c];
    ASTORE(&KVp[(size_t)(rowbase + r) * 256 + c], vk + bq[128 + c]);
    ASTORE(&KVp[(size_t)(rowbase + r) * 256 + 128 + c], vv + bq[256 + c]);
}

__global__ void __launch_bounds__(512, 1) mega_k(MegaArgs a) {
    __shared__ SM sm;
    const int t = threadIdx.x;
    const int bid = blockIdx.x;
    const int rowbase = bid * 4;
    const int b = rowbase >> 7;
    const int tfr = rowbase & 127;
    const int c = t & 127;
    const int rs = t >> 7;
    unsigned bctr = 0;
    unsigned* myctr = a.ctr + b * 16;

    const float4* embedp  = a.Wp + 294912;
    const float4* embed2p = a.Wp + 300160;
    const float4* sampp   = a.Wp + 305408;

    // ---- prologue: embed + qkv layer0 ----
    {
        int tf = tfr + rs;
        for (int j = c; j < 176; j += 128) {
            float val = 0.f;
            if (j < 33) val = a.posT[tf * 33 + j];
            else if (j < 161) {
                int o = j - 33;
                float p1 = a.P[((size_t)(b * 128 + o)) * 128 + tf];
                float p0 = (tf > 0) ? a.P[((size_t)(b * 128 + o)) * 128 + tf - 1] : 0.f;
                val = (p0 + p1) * (1.f / 512.f);
            }
            sm.cv[rs][j] = val;
        }
        __syncthreads();
        float acc1[1][4];
        gemm_acc<1>(&sm.cv[0][0], 176, embedp, 41, t, acc1);
        float v = gemm_reduce(acc1[0], t, sm) + a.embed_b[c];
        sm.Ax[rs][c] = v;
        __syncthreads();
        qkv_tail(a, sm, 0, t, rowbase);
        gbarb(myctr, bctr);
    }

    for (int l = 0; l < 12; ++l) {
        if (l == 6) {
            // ---- mid: env softmax + top16 + embed2 + qkv dec0 ----
            float v = (t < 128) ? ALOAD(&a.envbuf[b * 128 + t]) : -1e30f;
            float m_ = v;
#pragma unroll
            for (int mm = 1; mm <= 32; mm <<= 1) m_ = fmaxf(m_, __shfl_xor(m_, mm));
            if ((t & 63) == 0) sm.red2[(t >> 6) * 2] = m_;
            __syncthreads();
            float mx = fmaxf(sm.red2[0], sm.red2[2]);
            float e = (t < 128) ? expf(v - mx) : 0.f;
            float ssum = e;
#pragma unroll
            for (int mm = 1; mm <= 32; mm <<= 1) ssum += __shfl_xor(ssum, mm);
            __syncthreads();
            if ((t & 63) == 0) sm.red2[(t >> 6) * 2 + 1] = ssum;
            __syncthreads();
            float lsum = sm.red2[1] + sm.red2[3];
            if (t < 128) { sm.tvals[t] = e / lsum; sm.tout[t] = 0.f; }
            __syncthreads();
            for (int it = 0; it < 16; ++it) {
                float cv_ = (t < 128) ? sm.tvals[t] : -2.f;
                int ci = t & 127;
#pragma unroll
                for (int mm = 1; mm <= 32; mm <<= 1) {
                    float ov = __shfl_xor(cv_, mm);
                    int oi = __shfl_xor(ci, mm);
                    if (ov > cv_ || (ov == cv_ && oi < ci)) { cv_ = ov; ci = oi; }
                }
                if ((t & 63) == 0) { sm.red2[(t >> 6) * 2] = cv_; sm.red2i[t >> 6] = ci; }
                __syncthreads();
                if (t == 0) {
                    float v0 = sm.red2[0], v1 = sm.red2[2];
                    int i0 = sm.red2i[0], i1 = sm.red2i[1];
                    float bv; int bi2;
                    if (v1 > v0 || (v1 == v0 && i1 < i0)) { bv = v1; bi2 = i1; }
                    else { bv = v0; bi2 = i0; }
                    sm.tout[bi2] = bv;
                    sm.tvals[bi2] = -3.f;
                }
                __syncthreads();
            }
            float sclr = sm.tout[tfr + rs];
            for (int j = c; j < 176; j += 128) {
                float val = 0.f;
                if (j < 33) val = a.posT[(tfr + rs) * 33 + j];
                else if (j < 161) val = sm.Ax[rs][j - 33] * sclr;
                sm.cv[rs][j] = val;
            }
            __syncthreads();
            float acc1[1][4];
            gemm_acc<1>(&sm.cv[0][0], 176, embed2p, 41, t, acc1);
            float vv = gemm_reduce(acc1[0], t, sm) + a.embed2_b[c];
            sm.Ax[rs][c] = vv;
            __syncthreads();
            qkv_tail(a, sm, 6, t, rowbase);
            gbarb(myctr, bctr);
        }

        const float4* op  = a.Wp + 147456 + (size_t)l * 4096;
        const float4* w1p = a.Wp + 196608 + (size_t)l * 4096;
        const float4* w2p = a.Wp + 245760 + (size_t)l * 4096;
        const float* KVg = a.KV + (size_t)(l & 1) * 262144 + (size_t)b * 32768;

        // ---- A: attention (coalesced device-coherent loads -> LDS transpose) ----
        {
            float kst[32], vst[32];
#pragma unroll
            for (int j = 0; j < 32; ++j) {
                int f = j * 512 + t;
                kst[j] = ALOAD(&KVg[(size_t)(f >> 7) * 256 + (f & 127)]);
            }
#pragma unroll
            for (int j = 0; j < 32; ++j) {
                int f = j * 512 + t;
                vst[j] = ALOAD(&KVg[(size_t)(f >> 7) * 256 + 128 + (f & 127)]);
            }
            int cd = t & 127, r0 = t >> 7;
#pragma unroll
            for (int j = 0; j < 32; ++j) sm.KV[cd][j * 4 + r0] = kst[j];
            __syncthreads();
            {   // QK^T
                int h = t >> 7, k = c;
                float s0 = 0.f, s1 = 0.f, s2 = 0.f, s3 = 0.f;
#pragma unroll
                for (int d = 0; d < 32; ++d) {
                    float kvv = sm.KV[h * 32 + d][k];
                    s0 += sm.Aq[0][h * 32 + d] * kvv;
                    s1 += sm.Aq[1][h * 32 + d] * kvv;
                    s2 += sm.Aq[2][h * 32 + d] * kvv;
                    s3 += sm.Aq[3][h * 32 + d] * kvv;
                }
                const float scl = 0.17677669529663687f;
                sm.S[h * 4 + 0][k] = s0 * scl;
                sm.S[h * 4 + 1][k] = s1 * scl;
                sm.S[h * 4 + 2][k] = s2 * scl;
                sm.S[h * 4 + 3][k] = s3 * scl;
            }
            __syncthreads();
#pragma unroll
            for (int j = 0; j < 32; ++j) sm.KV[cd][j * 4 + r0] = vst[j];
            {   // softmax
                int row = t >> 5, l32 = t & 31;
                float v0 = sm.S[row][l32], v1 = sm.S[row][l32 + 32];
                float v2 = sm.S[row][l32 + 64], v3 = sm.S[row][l32 + 96];
                float mx = fmaxf(fmaxf(v0, v1), fmaxf(v2, v3));
#pragma unroll
                for (int mm = 1; mm <= 16; mm <<= 1) mx = fmaxf(mx, __shfl_xor(mx, mm));
                float e0 = __expf(v0 - mx), e1 = __expf(v1 - mx);
                float e2 = __expf(v2 - mx), e3 = __expf(v3 - mx);
                float ls = e0 + e1 + e2 + e3;
#pragma unroll
                for (int mm = 1; mm <= 16; mm <<= 1) ls += __shfl_xor(ls, mm);
                sm.S[row][l32] = e0; sm.S[row][l32 + 32] = e1;
                sm.S[row][l32 + 64] = e2; sm.S[row][l32 + 96] = e3;
                if (l32 == 0) sm.Linv[row] = 1.f / ls;
            }
            __syncthreads();
            {   // PV
                int h = t >> 7, r = (t >> 5) & 3, d = t & 31;
                const float* Pr = &sm.S[h * 4 + r][0];
                float o = 0.f;
#pragma unroll 8
                for (int k2 = 0; k2 < 128; ++k2) o += Pr[k2] * sm.KV[h * 32 + d][k2];
                sm.Ah[r][h * 32 + d] = o * sm.Linv[h * 4 + r];
            }
            __syncthreads();
        }
        // ---- D: o-proj + residual + ln1 ----
        {
            float acc1[1][4];
            gemm_acc<1>(&sm.Ah[0][0], 128, op, 32, t, acc1);
            float v = gemm_reduce(acc1[0], t, sm);
            v += a.b_o[l][c] + sm.Ax[rs][c];
            v = lnorm(v, t, a.ln1g[l], a.ln1b[l], sm);
            sm.Ax2[rs][c] = v;
            __syncthreads();
        }
        // ---- E/F: ffn + residual + ln2 ----
        {
            float acc1[1][4];
            gemm_acc<1>(&sm.Ax2[0][0], 128, w1p, 32, t, acc1);
            float v = fmaxf(gemm_reduce(acc1[0], t, sm) + a.b1[l][c], 0.f);
            sm.Ah[rs][c] = v;
            __syncthreads();
            float acc2[1][4];
            gemm_acc<1>(&sm.Ah[0][0], 128, w2p, 32, t, acc2);
            float v2 = gemm_reduce(acc2[0], t, sm) + a.b2[l][c] + sm.Ax2[rs][c];
            v2 = lnorm(v2, t, a.ln2g[l], a.ln2b[l], sm);
            sm.Ax[rs][c] = v2;
            __syncthreads();
        }
        // ---- G: tail ----
        if (l == 5) {
            float pv = sm.Ax[rs][c] * a.env_w[c];
#pragma unroll
            for (int mm = 1; mm <= 32; mm <<= 1) pv += __shfl_xor(pv, mm);
            int w = t >> 6;
            if ((t & 63) == 0) sm.red2[w * 2] = pv;
            __syncthreads();
            if (t < 4) ASTORE(&a.envbuf[rowbase + t],
                              sm.red2[(2 * t) * 2] + sm.red2[(2 * t + 1) * 2] + a.env_b[0]);
            __syncthreads();
        } else if (l == 11) {
            // samp: fused single-barrier 4-output reduce in dead KV region
            float acc4[4][4];
            gemm_acc<4>(&sm.Ax[0][0], 128, sampp, 32, t, acc4);
            float* part = &sm.KV[0][0];   // 64x128 floats
            int kq = rs;
#pragma unroll
            for (int i = 0; i < 4; ++i)
#pragma unroll
                for (int r = 0; r < 4; ++r)
                    part[((i * 4 + r) * 4 + kq) * 128 + c] = acc4[i][r];
            __syncthreads();
#pragma unroll
            for (int i = 0; i < 4; ++i) {
                float v = 0.f;
#pragma unroll
                for (int q = 0; q < 4; ++q) v += part[((i * 4 + rs) * 4 + q) * 128 + c];
                int cg = c + i * 128;
                v = (v + a.samp_b[cg]) * a.ham[cg];
                ASTORE(&a.Y[((size_t)(rowbase + rs)) * 512 + cg], v);
            }
        } else {
            qkv_tail(a, sm, l + 1, t, rowbase);
        }
        gbarb(myctr, bctr);
    }

    // ---- overlap-add (batch-local) ----
    {
        int b32 = bid & 31;
#pragma unroll
        for (int i = 0; i < 2; ++i) {
            int il = b32 * 512 + t + i * 16384;
            int t0 = il >> 8, w0 = il & 255;
            float acc = ALOAD(&a.Y[((size_t)(b * 128 + t0)) * 512 + w0]);
            if (t0 > 0) acc += ALOAD(&a.Y[((size_t)(b * 128 + t0 - 1)) * 512 + w0 + 256]);
            a.out[(size_t)b * 32768 + il] = acc;
        }
    }
}

extern "C" void kernel_launch(void* const* d_in, const int* in_sizes, int n_in,
                              void* d_out, int out_size, void* d_ws, size_t ws_size,
                              hipStream_t stream) {
    const float* x        = (const float*)d_in[0];
    const float* filters  = (const float*)d_in[1];
    const float* embed_w  = (const float*)d_in[2];
    const float* embed_b  = (const float*)d_in[3];
    const float* embed2_w = (const float*)d_in[4];
    const float* embed2_b = (const float*)d_in[5];
    const float* env_w    = (const float*)d_in[6];
    const float* env_b    = (const float*)d_in[7];
    const float* samp_w   = (const float*)d_in[8];
    const float* samp_b   = (const float*)d_in[9];

    float* ws = (float*)d_ws;
    float* P     = ws;                      // 131072
    float* posT  = ws + 131072;             // 4352
    float* hamw  = ws + 135424;             // 512
    float* envb  = ws + 135936;             // 1024
    float* KV    = ws + 136960;             // 524288 (2 parities x 1024 x 256)
    float* Y     = ws + 661248;             // 524288
    float4* Wp   = (float4*)(ws + 1185536); // 321792 float4
    unsigned* ctr = (unsigned*)(ws + 2472704);
    // conv-prep aliases (dead regions at conv time)
    unsigned short* xhi = (unsigned short*)Y;
    unsigned short* xlo = (unsigned short*)(Y + 131072);
    unsigned short* Fph = (unsigned short*)KV;
    unsigned short* Fpl = (unsigned short*)(KV + 32768);

    PackPtrs pp;
    for (int l = 0; l < 12; ++l) {
        int base = (l < 6) ? 10 + l * 12 : 82 + (l - 6) * 12;
        pp.p[l]      = (const float*)d_in[base + 0];
        pp.p[12 + l] = (const float*)d_in[base + 2];
        pp.p[24 + l] = (const float*)d_in[base + 4];
        pp.p[36 + l] = (const float*)d_in[base + 6];
    }
    pp.p[48] = embed_w; pp.p[49] = embed2_w; pp.p[50] = samp_w;

    prep_k<<<4545, 256, 0, stream>>>(x, filters, xhi, xlo, Fph, Fpl, posT, hamw,
                                     pp, Wp, ctr);
    conv_mfma_k<<<dim3(64, 8), 512, 0, stream>>>(xhi, xlo, Fph, Fpl, P);

    MegaArgs ma;
    for (int l = 0; l < 12; ++l) {
        int base = (l < 6) ? 10 + l * 12 : 82 + (l - 6) * 12;
        ma.b_qkv[l] = (const float*)d_in[base + 1];
        ma.b_o[l]   = (const float*)d_in[base + 3];
        ma.b1[l]    = (const float*)d_in[base + 5];
        ma.b2[l]    = (const float*)d_in[base + 7];
        ma.ln1g[l]  = (const float*)d_in[base + 8];
        ma.ln1b[l]  = (const float*)d_in[base + 9];
        ma.ln2g[l]  = (const float*)d_in[base + 10];
        ma.ln2b[l]  = (const float*)d_in[base + 11];
    }
    ma.embed_b = embed_b; ma.embed2_b = embed2_b;
    ma.env_w = env_w; ma.env_b = env_b; ma.samp_b = samp_b;
    ma.posT = posT; ma.ham = hamw; ma.P = P;
    ma.Wp = (const float4*)Wp;
    ma.KV = KV; ma.envbuf = envb; ma.Y = Y; ma.out = (float*)d_out;
    ma.ctr = ctr;

    mega_k<<<256, 512, 0, stream>>>(ma);
}